// Round 1
// baseline (5736.779 us; speedup 1.0000x reference)
//
#include <hip/hip_runtime.h>

#define SS 16
#define SP 65536   // 16^4

// Y = relu(conv4d(X, W) + b) + relu(conv4d_pairT(X, W) + b)
// conv1: out[o,h1,w1,h2,w2] += x[c,h1+i-PA,w1+j-PB,h2+k-PC,w2+l-PD] * w[o,c,i,j,k,l]
// conv2: out[o,h1,w1,h2,w2] += x[c,h1+i-PC,w1+j-PD,h2+k-PA,w2+l-PB] * w[o,c,k,l,i,j]
template<int C, int O, int KA, int KB, int KC, int KD>
__global__ __launch_bounds__(256)
void conv4d_sym_kernel(const float* __restrict__ X, int xBatchStride,
                       const float* __restrict__ W, const float* __restrict__ Bv,
                       float* __restrict__ Y, int yBatchStride)
{
    constexpr int PA = KA/2, PB = KB/2, PC = KC/2, PD = KD/2;
    constexpr int R  = 2;                 // covers max pad (kernels are 3 or 5)
    constexpr int PW = SS + 2*R;          // 20 (padded plane width)
    static_assert(PA <= R && PB <= R && PC <= R && PD <= R, "pad radius");
    __shared__ float lds[(2*R+1)*(2*R+1)*PW*PW];   // 25*400*4 = 40000 B

    const int blk = blockIdx.x;
    const int w1 = blk & 15, h1 = (blk >> 4) & 15, b = blk >> 8;
    const int tid = threadIdx.x;
    const int w2 = tid & 15, h2 = tid >> 4;

    float acc1[O], acc2[O];
    #pragma unroll
    for (int o = 0; o < O; ++o) { acc1[o] = 0.f; acc2[o] = 0.f; }

    for (int c = 0; c < C; ++c) {
        __syncthreads();   // protect previous iteration's readers
        const float* Xc = X + (size_t)b * xBatchStride + (size_t)c * SP;
        for (int idx = tid; idx < 25*PW*PW; idx += 256) {
            int p   = idx / (PW*PW);
            int rem = idx - p*(PW*PW);
            int r   = rem / PW;
            int q   = rem - r*PW;
            int hh1 = h1 + p/5 - R;
            int ww1 = w1 + p%5 - R;
            int hh2 = r - R;
            int ww2 = q - R;
            float v = 0.f;
            if ((unsigned)hh1 < SS && (unsigned)ww1 < SS &&
                (unsigned)hh2 < SS && (unsigned)ww2 < SS)
                v = Xc[((hh1*SS + ww1)*SS + hh2)*SS + ww2];
            lds[idx] = v;
        }
        __syncthreads();

        // ---- conv1: outer taps (i,j) over (KA,KB), inner (k,l) over (KC,KD)
        for (int i = 0; i < KA; ++i)
        for (int j = 0; j < KB; ++j) {
            const int p = (i - PA + R)*5 + (j - PB + R);
            const float* base = &lds[p*PW*PW];
            float xr[KC*KD];
            #pragma unroll
            for (int k = 0; k < KC; ++k)
            #pragma unroll
            for (int l = 0; l < KD; ++l)
                xr[k*KD + l] = base[(h2 + k - PC + R)*PW + (w2 + l - PD + R)];
            #pragma unroll
            for (int o = 0; o < O; ++o) {
                const float* wp = W + ((((size_t)o*C + c)*KA + i)*KB + j)*(KC*KD);
                float a = 0.f;
                #pragma unroll
                for (int t = 0; t < KC*KD; ++t)
                    a = fmaf(xr[t], wp[t], a);
                acc1[o] += a;
            }
        }

        // ---- conv2 (pair-transposed weight): outer (i,j) over (KC,KD), inner (k,l) over (KA,KB)
        for (int i = 0; i < KC; ++i)
        for (int j = 0; j < KD; ++j) {
            const int p = (i - PC + R)*5 + (j - PD + R);
            const float* base = &lds[p*PW*PW];
            float xr[KA*KB];
            #pragma unroll
            for (int k = 0; k < KA; ++k)
            #pragma unroll
            for (int l = 0; l < KB; ++l)
                xr[k*KB + l] = base[(h2 + k - PA + R)*PW + (w2 + l - PB + R)];
            #pragma unroll
            for (int o = 0; o < O; ++o) {
                float a = 0.f;
                #pragma unroll
                for (int k = 0; k < KA; ++k)
                #pragma unroll
                for (int l = 0; l < KB; ++l)
                    a = fmaf(xr[k*KB + l],
                             W[((((size_t)o*C + c)*KA + k)*KB + l)*(KC*KD) + i*KD + j],
                             a);
                acc2[o] += a;
            }
        }
    }

    const int pos = (blk & 255)*256 + tid;   // (h1*16+w1)*256 + h2*16+w2
    #pragma unroll
    for (int o = 0; o < O; ++o) {
        float y1 = acc1[o] + Bv[o]; y1 = y1 > 0.f ? y1 : 0.f;
        float y2 = acc2[o] + Bv[o]; y2 = y2 > 0.f ? y2 : 0.f;
        Y[(size_t)b*yBatchStride + (size_t)o*SP + pos] = y1 + y2;
    }
}

extern "C" void kernel_launch(void* const* d_in, const int* in_sizes, int n_in,
                              void* d_out, int out_size, void* d_ws, size_t ws_size,
                              hipStream_t stream) {
    const float* x   = (const float*)d_in[0];
    const float* w00 = (const float*)d_in[1];
    const float* b00 = (const float*)d_in[2];
    const float* w01 = (const float*)d_in[3];
    const float* b01 = (const float*)d_in[4];
    const float* w10 = (const float*)d_in[5];
    const float* b10 = (const float*)d_in[6];
    const float* w11 = (const float*)d_in[7];
    const float* b11 = (const float*)d_in[8];
    const float* w2  = (const float*)d_in[9];
    const float* b2  = (const float*)d_in[10];

    const int B = in_sizes[0] / SP;          // x is (B,1,16,16,16,16)
    float* X1 = (float*)d_ws;                          // (B,16,16^4) = 16 MB @ B=4
    float* X2 = X1 + (size_t)B * 16 * SP;              // (B,16,16^4) = 16 MB

    dim3 block(256);
    dim3 grid(B * 256);

    hipLaunchKernelGGL((conv4d_sym_kernel<1, 8, 3, 3, 5, 5>), grid, block, 0, stream,
                       x, SP, w00, b00, X1,          16*SP);
    hipLaunchKernelGGL((conv4d_sym_kernel<1, 8, 5, 5, 5, 5>), grid, block, 0, stream,
                       x, SP, w01, b01, X1 + 8*SP,   16*SP);
    hipLaunchKernelGGL((conv4d_sym_kernel<16, 8, 3, 3, 5, 5>), grid, block, 0, stream,
                       X1, 16*SP, w10, b10, X2,        16*SP);
    hipLaunchKernelGGL((conv4d_sym_kernel<16, 8, 5, 5, 5, 5>), grid, block, 0, stream,
                       X1, 16*SP, w11, b11, X2 + 8*SP, 16*SP);
    hipLaunchKernelGGL((conv4d_sym_kernel<16, 1, 5, 5, 5, 5>), grid, block, 0, stream,
                       X2, 16*SP, w2, b2, (float*)d_out, SP);
}

// Round 2
// 427.934 us; speedup vs baseline: 13.4058x; 13.4058x over previous
//
#include <hip/hip_runtime.h>
#include <hip/hip_bf16.h>

#define SS 16
#define SP 65536   // 16^4

typedef __attribute__((ext_vector_type(8))) short short8;
typedef __attribute__((ext_vector_type(4))) float f32x4;

// ---------------------------------------------------------------------------
// Layer-1: fp32 vector conv (C=1), writes bf16 channel-last (B,h1,w1,h2,w2,16)
// Y = relu(conv4d(X,W)+b) + relu(conv4d_pairT(X,W)+b)
// ---------------------------------------------------------------------------
template<int C, int O, int KA, int KB, int KC, int KD>
__global__ __launch_bounds__(256)
void conv4d_sym_l1(const float* __restrict__ X, int xBatchStride,
                   const float* __restrict__ W, const float* __restrict__ Bv,
                   __hip_bfloat16* __restrict__ Y, int obase)
{
    constexpr int PA = KA/2, PB = KB/2, PC = KC/2, PD = KD/2;
    constexpr int R  = 2;
    constexpr int PW = SS + 2*R;          // 20
    __shared__ float lds[(2*R+1)*(2*R+1)*PW*PW];   // 40000 B

    const int blk = blockIdx.x;
    const int w1 = blk & 15, h1 = (blk >> 4) & 15, b = blk >> 8;
    const int tid = threadIdx.x;
    const int w2 = tid & 15, h2 = tid >> 4;

    float acc1[O], acc2[O];
    #pragma unroll
    for (int o = 0; o < O; ++o) { acc1[o] = 0.f; acc2[o] = 0.f; }

    for (int c = 0; c < C; ++c) {
        __syncthreads();
        const float* Xc = X + (size_t)b * xBatchStride + (size_t)c * SP;
        for (int idx = tid; idx < 25*PW*PW; idx += 256) {
            int p   = idx / (PW*PW);
            int rem = idx - p*(PW*PW);
            int r   = rem / PW;
            int q   = rem - r*PW;
            int hh1 = h1 + p/5 - R;
            int ww1 = w1 + p%5 - R;
            int hh2 = r - R;
            int ww2 = q - R;
            float v = 0.f;
            if ((unsigned)hh1 < SS && (unsigned)ww1 < SS &&
                (unsigned)hh2 < SS && (unsigned)ww2 < SS)
                v = Xc[((hh1*SS + ww1)*SS + hh2)*SS + ww2];
            lds[idx] = v;
        }
        __syncthreads();

        for (int i = 0; i < KA; ++i)
        for (int j = 0; j < KB; ++j) {
            const int p = (i - PA + R)*5 + (j - PB + R);
            const float* base = &lds[p*PW*PW];
            float xr[KC*KD];
            #pragma unroll
            for (int k = 0; k < KC; ++k)
            #pragma unroll
            for (int l = 0; l < KD; ++l)
                xr[k*KD + l] = base[(h2 + k - PC + R)*PW + (w2 + l - PD + R)];
            #pragma unroll
            for (int o = 0; o < O; ++o) {
                const float* wp = W + ((((size_t)o*C + c)*KA + i)*KB + j)*(KC*KD);
                float a = 0.f;
                #pragma unroll
                for (int t = 0; t < KC*KD; ++t)
                    a = fmaf(xr[t], wp[t], a);
                acc1[o] += a;
            }
        }

        for (int i = 0; i < KC; ++i)
        for (int j = 0; j < KD; ++j) {
            const int p = (i - PC + R)*5 + (j - PD + R);
            const float* base = &lds[p*PW*PW];
            float xr[KA*KB];
            #pragma unroll
            for (int k = 0; k < KA; ++k)
            #pragma unroll
            for (int l = 0; l < KB; ++l)
                xr[k*KB + l] = base[(h2 + k - PA + R)*PW + (w2 + l - PB + R)];
            #pragma unroll
            for (int o = 0; o < O; ++o) {
                float a = 0.f;
                #pragma unroll
                for (int k = 0; k < KA; ++k)
                #pragma unroll
                for (int l = 0; l < KB; ++l)
                    a = fmaf(xr[k*KB + l],
                             W[((((size_t)o*C + c)*KA + k)*KB + l)*(KC*KD) + i*KD + j],
                             a);
                acc2[o] += a;
            }
        }
    }

    const int pos = (blk & 255)*256 + tid;   // (h1*16+w1)*256 + h2*16+w2
    #pragma unroll
    for (int o = 0; o < O; ++o) {
        float y1 = acc1[o] + Bv[o]; y1 = y1 > 0.f ? y1 : 0.f;
        float y2 = acc2[o] + Bv[o]; y2 = y2 > 0.f ? y2 : 0.f;
        Y[((size_t)b*SP + pos)*16 + obase + o] = __float2bfloat16(y1 + y2);
    }
}

// ---------------------------------------------------------------------------
// Prep: build B-fragments (bf16) in MFMA register layout.
// Bws[p][f][lane][j] = B[k = f*32 + (lane>>4)*8 + j][n = lane&15]
// Stream per plane p=(pi,pj): if conv1-active: 25 shifts (5x5 union) x 16 ch,
// else KA*KB shifts x 16 ch. n<8: conv1 w[o,c,i',j',k,l]; n>=8: conv2
// w[o,c,k,l,i',j'] (only if shift inside KAxKB window).
// ---------------------------------------------------------------------------
template<int O, int KA, int KB>
__global__ __launch_bounds__(256)
void prep_bfrag(const float* __restrict__ W, __hip_bfloat16* __restrict__ Bws)
{
    constexpr int PA = KA/2, PB = KB/2;
    int t = blockIdx.x * 256 + threadIdx.x;
    if (t >= 25*13*64) return;
    int lane = t & 63;
    int f = (t >> 6) % 13;
    int p = t / (64*13);
    int pi = p/5, pj = p%5;
    bool c1a = (pi >= 2-PA && pi <= 2+PA && pj >= 2-PB && pj <= 2+PB);
    int slen = c1a ? 400 : KA*KB*16;
    int n = lane & 15;
    __hip_bfloat16 vals[8];
    #pragma unroll
    for (int j = 0; j < 8; ++j) {
        int kk = f*32 + ((lane>>4)*8) + j;
        float v = 0.f;
        if (kk < slen) {
            int sp = kk >> 4, c = kk & 15;
            int dsh, dsw;
            if (c1a) { dsh = sp/5 - 2;  dsw = sp%5 - 2;  }
            else     { dsh = sp/KB - PA; dsw = sp%KB - PB; }
            if (n < 8) {
                if (c1a && n < O)
                    v = W[((((size_t)(n*16 + c)*KA + (pi-2+PA))*KB + (pj-2+PB))*5 + (dsh+2))*5 + (dsw+2)];
            } else {
                int o = n - 8;
                if (o < O && dsh >= -PA && dsh <= PA && dsw >= -PB && dsw <= PB)
                    v = W[((((size_t)(o*16 + c)*KA + (dsh+PA))*KB + (dsw+PB))*5 + pi)*5 + pj];
            }
        }
        vals[j] = __float2bfloat16(v);
    }
    *reinterpret_cast<short8*>(Bws + (size_t)t * 8) = *reinterpret_cast<const short8*>(vals);
}

// ---------------------------------------------------------------------------
// MFMA conv kernel (C=16). Block = (b,h1,w1), 4 waves, wave = 4 M-tiles (h2).
// LDS plane: [half][20 h2][20 w2][8 ch] bf16 = 12800 B, halo pre-zeroed.
// ---------------------------------------------------------------------------
__device__ inline void load_plane_regs(const __hip_bfloat16* __restrict__ X,
                                       int b, int h1, int w1, int p, int tid,
                                       short8& s0, short8& s1)
{
    int pi = p/5, pj = p%5;
    int hh = h1 + pi - 2, ww = w1 + pj - 2;
    short8 z = {};
    if ((unsigned)hh < 16u && (unsigned)ww < 16u) {
        const short8* src = reinterpret_cast<const short8*>(X)
                          + ((size_t)((b*16 + hh)*16 + ww) << 9);  // 512 short8 per plane
        s0 = src[tid];
        s1 = src[tid + 256];
    } else { s0 = z; s1 = z; }
}

template<int O, int KA, int KB, bool OUTBF16>
__global__ __launch_bounds__(256)
void conv_mfma(const __hip_bfloat16* __restrict__ X,
               const __hip_bfloat16* __restrict__ Bws,
               const float* __restrict__ bias,
               void* __restrict__ Yout, int obase)
{
    constexpr int PA = KA/2, PB = KB/2;
    constexpr bool FULLALL = (KA == 5 && KB == 5);
    constexpr int NFC = 13;                        // ceil(400/32)
    constexpr int NFO = (KA*KB*16 + 31)/32;        // conv2-only stream
    __shared__ __align__(16) char lbuf[12800];

    const int tid = threadIdx.x, lane = tid & 63, wid = tid >> 6;
    const int blk = blockIdx.x;
    const int w1 = blk & 15, h1 = (blk >> 4) & 15, b = blk >> 8;
    const int g = lane >> 4, lane15 = lane & 15;

    for (int i = tid; i < 3200; i += 256) reinterpret_cast<int*>(lbuf)[i] = 0;

    // Per-lane LDS byte offsets for each fragment's k-subgroup
    unsigned offsC[NFC];
    #pragma unroll
    for (int f = 0; f < NFC; ++f) {
        int kk = f*32 + g*8;
        unsigned off = 0;
        if (kk < 400) {
            int sp = kk >> 4, half = (kk >> 3) & 1;
            int dsh = sp/5 - 2, dsw = sp%5 - 2;
            off = (unsigned)(half*6400 + ((dsh+2)*20 + (dsw+2))*16);
        }
        offsC[f] = off;
    }
    unsigned offsO[NFO];
    if (!FULLALL) {
        #pragma unroll
        for (int f = 0; f < NFO; ++f) {
            int kk = f*32 + g*8;
            unsigned off = 0;
            if (kk < KA*KB*16) {
                int sp = kk >> 4, half = (kk >> 3) & 1;
                int dsh = sp/KB - PA, dsw = sp%KB - PB;
                off = (unsigned)(half*6400 + ((dsh+2)*20 + (dsw+2))*16);
            }
            offsO[f] = off;
        }
    }

    f32x4 acc[4] = {{0,0,0,0},{0,0,0,0},{0,0,0,0},{0,0,0,0}};
    const unsigned aterm = (unsigned)(lane15*16 + wid*4*320);

    // staging destinations (entry e: pos=e>>1, half=e&1)
    const int dst0 = (tid&1)*6400 + (((tid>>1)>>4)+2)*320 + (((tid>>1)&15)+2)*16;
    const int dst1 = dst0 + 2560;   // +128 positions = +8 h2 rows

    short8 st0, st1;
    load_plane_regs(X, b, h1, w1, 0, tid, st0, st1);

    for (int p = 0; p < 25; ++p) {
        __syncthreads();
        *reinterpret_cast<short8*>(lbuf + dst0) = st0;
        *reinterpret_cast<short8*>(lbuf + dst1) = st1;
        __syncthreads();
        if (p < 24) load_plane_regs(X, b, h1, w1, p+1, tid, st0, st1);

        int pi = p/5, pj = p%5;
        const short8* bp = reinterpret_cast<const short8*>(Bws) + (size_t)p*13*64 + lane;
        bool center = FULLALL || (pi >= 2-PA && pi <= 2+PA && pj >= 2-PB && pj <= 2+PB);
        if (center) {
            #pragma unroll
            for (int f = 0; f < NFC; ++f) {
                short8 bf = bp[f*64];
                #pragma unroll
                for (int mt = 0; mt < 4; ++mt) {
                    short8 a = *reinterpret_cast<const short8*>(lbuf + offsC[f] + aterm + mt*320);
                    acc[mt] = __builtin_amdgcn_mfma_f32_16x16x32_bf16(a, bf, acc[mt], 0, 0, 0);
                }
            }
        } else {
            #pragma unroll
            for (int f = 0; f < NFO; ++f) {
                short8 bf = bp[f*64];
                #pragma unroll
                for (int mt = 0; mt < 4; ++mt) {
                    short8 a = *reinterpret_cast<const short8*>(lbuf + offsO[f] + aterm + mt*320);
                    acc[mt] = __builtin_amdgcn_mfma_f32_16x16x32_bf16(a, bf, acc[mt], 0, 0, 0);
                }
            }
        }
    }

    // Epilogue: D col=lane&15 (n), row=(lane>>4)*4+reg (w2). Pair n <-> n+8.
    const int o = lane15 & 7;
    const float bv = (o < O) ? bias[o] : 0.f;
    #pragma unroll
    for (int mt = 0; mt < 4; ++mt) {
        #pragma unroll
        for (int r = 0; r < 4; ++r) {
            float own = acc[mt][r];
            float oth = __shfl_xor(own, 8);
            if (lane15 < 8 && o < O) {
                float y = fmaxf(own + bv, 0.f) + fmaxf(oth + bv, 0.f);
                int h2 = wid*4 + mt, w2 = g*4 + r;
                size_t pos = (((size_t)b*256 + h1*16 + w1) << 8) + h2*16 + w2;
                if (OUTBF16)
                    reinterpret_cast<__hip_bfloat16*>(Yout)[pos*16 + obase + o] = __float2bfloat16(y);
                else
                    reinterpret_cast<float*>(Yout)[pos] = y;
            }
        }
    }
}

// ---------------------------------------------------------------------------
extern "C" void kernel_launch(void* const* d_in, const int* in_sizes, int n_in,
                              void* d_out, int out_size, void* d_ws, size_t ws_size,
                              hipStream_t stream) {
    const float* x   = (const float*)d_in[0];
    const float* w00 = (const float*)d_in[1];
    const float* b00 = (const float*)d_in[2];
    const float* w01 = (const float*)d_in[3];
    const float* b01 = (const float*)d_in[4];
    const float* w10 = (const float*)d_in[5];
    const float* b10 = (const float*)d_in[6];
    const float* w11 = (const float*)d_in[7];
    const float* b11 = (const float*)d_in[8];
    const float* w2  = (const float*)d_in[9];
    const float* b2  = (const float*)d_in[10];

    const int B = in_sizes[0] / SP;   // 4

    __hip_bfloat16* X1   = (__hip_bfloat16*)d_ws;                 // B*SP*16 bf16
    __hip_bfloat16* X2   = X1 + (size_t)B * SP * 16;              // B*SP*16 bf16
    __hip_bfloat16* Bw10 = X2 + (size_t)B * SP * 16;              // 25*13*64*8
    __hip_bfloat16* Bw11 = Bw10 + 25*13*64*8;
    __hip_bfloat16* Bw2  = Bw11 + 25*13*64*8;

    dim3 blockP(256), gridP(82);   // 25*13*64 = 20800 threads
    hipLaunchKernelGGL((prep_bfrag<8,3,3>), gridP, blockP, 0, stream, w10, Bw10);
    hipLaunchKernelGGL((prep_bfrag<8,5,5>), gridP, blockP, 0, stream, w11, Bw11);
    hipLaunchKernelGGL((prep_bfrag<1,5,5>), gridP, blockP, 0, stream, w2,  Bw2);

    dim3 block(256), grid(B * 256);
    hipLaunchKernelGGL((conv4d_sym_l1<1,8,3,3,5,5>), grid, block, 0, stream,
                       x, SP, w00, b00, X1, 0);
    hipLaunchKernelGGL((conv4d_sym_l1<1,8,5,5,5,5>), grid, block, 0, stream,
                       x, SP, w01, b01, X1, 8);

    hipLaunchKernelGGL((conv_mfma<8,3,3,true>),  grid, block, 0, stream,
                       X1, Bw10, b10, (void*)X2, 0);
    hipLaunchKernelGGL((conv_mfma<8,5,5,true>),  grid, block, 0, stream,
                       X1, Bw11, b11, (void*)X2, 8);
    hipLaunchKernelGGL((conv_mfma<1,5,5,false>), grid, block, 0, stream,
                       X2, Bw2,  b2,  d_out, 0);
}

// Round 3
// 260.834 us; speedup vs baseline: 21.9940x; 1.6406x over previous
//
#include <hip/hip_runtime.h>
#include <hip/hip_bf16.h>

#define SS 16
#define SP 65536   // 16^4

typedef __attribute__((ext_vector_type(8))) short short8;
typedef __attribute__((ext_vector_type(4))) float f32x4;

// ---------------------------------------------------------------------------
// Xim: [b][h1][w1][h2][w2][32] bf16. Slot s = k*5+l <-> inner shift (k-2, l-2)
// over (h2,w2); s >= 25 is zero padding (also zero-masked in B fragments).
// ---------------------------------------------------------------------------
__global__ __launch_bounds__(256)
void build_xim(const float* __restrict__ X, __hip_bfloat16* __restrict__ Xim, int total)
{
    int t = blockIdx.x * 256 + threadIdx.x;       // t = pos*4 + g
    if (t >= total) return;
    int g   = t & 3;
    int pos = t >> 2;                              // ((b*16+h1)*16+w1)*256 + h2*16 + w2
    int w2 = pos & 15, h2 = (pos >> 4) & 15;
    const float* xp = X + ((size_t)(pos >> 8) << 8);   // (b,h1,w1) plane base
    __hip_bfloat16 vals[8];
    #pragma unroll
    for (int j = 0; j < 8; ++j) {
        int s = g*8 + j;
        float v = 0.f;
        if (s < 25) {
            int hh = h2 + s/5 - 2, ww = w2 + s%5 - 2;
            if ((unsigned)hh < 16u && (unsigned)ww < 16u)
                v = xp[hh*16 + ww];
        }
        vals[j] = __float2bfloat16(v);
    }
    *reinterpret_cast<short8*>(Xim + (size_t)t * 8) = *reinterpret_cast<const short8*>(vals);
}

// ---------------------------------------------------------------------------
// Layer-1 B fragments: Bf[p][lane][j] = B[k = (lane>>4)*8+j][n = lane&15]
// n<8: conv1 o=n, weight w[o,0,pi-2+PA,pj-2+PB,kk,ll] (valid planes only)
// n>=8: conv2 o=n-8, weight w[o,0,kk-2+PA,ll-2+PB,pi,pj] (valid inner shifts)
// ---------------------------------------------------------------------------
template<int KA, int KB>
__global__ __launch_bounds__(256)
void prep_bl1(const float* __restrict__ W, __hip_bfloat16* __restrict__ Bf)
{
    constexpr int PA = KA/2, PB = KB/2;
    int t = blockIdx.x * 256 + threadIdx.x;
    if (t >= 25*64) return;
    int lane = t & 63, p = t >> 6;
    int pi = p/5, pj = p%5;
    int n = lane & 15;
    __hip_bfloat16 vals[8];
    #pragma unroll
    for (int j = 0; j < 8; ++j) {
        int s = (lane >> 4)*8 + j;
        float v = 0.f;
        if (s < 25) {
            int kk = s/5, ll = s%5;
            if (n < 8) {
                int i = pi - 2 + PA, jj = pj - 2 + PB;
                if ((unsigned)i < (unsigned)KA && (unsigned)jj < (unsigned)KB)
                    v = W[(((n*KA + i)*KB + jj)*5 + kk)*5 + ll];
            } else {
                int k2 = kk - 2 + PA, l2 = ll - 2 + PB;
                if ((unsigned)k2 < (unsigned)KA && (unsigned)l2 < (unsigned)KB)
                    v = W[((((n-8)*KA + k2)*KB + l2)*5 + pi)*5 + pj];
            }
        }
        vals[j] = __float2bfloat16(v);
    }
    *reinterpret_cast<short8*>(Bf + (size_t)t * 8) = *reinterpret_cast<const short8*>(vals);
}

// ---------------------------------------------------------------------------
// Layer-1 MFMA: no LDS, A direct from Xim (coalesced b128), two B streams
// (w00-pair, w01-pair) share every A fragment. Writes X1 channel-last.
// ---------------------------------------------------------------------------
__global__ __launch_bounds__(256)
void conv_mfma_l1(const __hip_bfloat16* __restrict__ Xim,
                  const __hip_bfloat16* __restrict__ B0,
                  const __hip_bfloat16* __restrict__ B1,
                  const float* __restrict__ bias0,
                  const float* __restrict__ bias1,
                  __hip_bfloat16* __restrict__ Y)
{
    const int tid = threadIdx.x, lane = tid & 63, wid = tid >> 6;
    int blk = (blockIdx.x & 7) * (gridDim.x >> 3) + (blockIdx.x >> 3);  // XCD swizzle
    const int w1 = blk & 15, h1 = (blk >> 4) & 15, b = blk >> 8;
    const int g = lane >> 4, lane15 = lane & 15;

    f32x4 acc0[4] = {{0,0,0,0},{0,0,0,0},{0,0,0,0},{0,0,0,0}};
    f32x4 acc1[4] = {{0,0,0,0},{0,0,0,0},{0,0,0,0},{0,0,0,0}};
    const short8* BB0 = reinterpret_cast<const short8*>(B0);
    const short8* BB1 = reinterpret_cast<const short8*>(B1);

    for (int p = 0; p < 25; ++p) {
        int hh = h1 + p/5 - 2, ww = w1 + p%5 - 2;
        if ((unsigned)hh >= 16u || (unsigned)ww >= 16u) continue;   // block-uniform
        const short8* ap = reinterpret_cast<const short8*>(Xim)
                         + ((size_t)((b*16 + hh)*16 + ww) << 10);   // *256 pos *4 frags
        short8 b0 = BB0[p*64 + lane];
        short8 b1 = BB1[p*64 + lane];
        #pragma unroll
        for (int mt = 0; mt < 4; ++mt) {
            short8 a = ap[(((wid*4 + mt)*16 + lane15) << 2) + g];
            acc0[mt] = __builtin_amdgcn_mfma_f32_16x16x32_bf16(a, b0, acc0[mt], 0, 0, 0);
            acc1[mt] = __builtin_amdgcn_mfma_f32_16x16x32_bf16(a, b1, acc1[mt], 0, 0, 0);
        }
    }

    const int o = lane15 & 7;
    const float bv0 = bias0[o], bv1 = bias1[o];
    #pragma unroll
    for (int mt = 0; mt < 4; ++mt) {
        #pragma unroll
        for (int r = 0; r < 4; ++r) {
            float own0 = acc0[mt][r], oth0 = __shfl_xor(own0, 8);
            float own1 = acc1[mt][r], oth1 = __shfl_xor(own1, 8);
            if (lane15 < 8) {
                float y0 = fmaxf(own0 + bv0, 0.f) + fmaxf(oth0 + bv0, 0.f);
                float y1 = fmaxf(own1 + bv1, 0.f) + fmaxf(oth1 + bv1, 0.f);
                int h2 = wid*4 + mt, w2v = g*4 + r;
                size_t pos = ((size_t)blk << 8) + h2*16 + w2v;
                Y[pos*16 + o]     = __float2bfloat16(y0);
                Y[pos*16 + 8 + o] = __float2bfloat16(y1);
            }
        }
    }
}

// ---------------------------------------------------------------------------
// Layer-2/3 B-fragment prep (unchanged from round 2)
// ---------------------------------------------------------------------------
template<int O, int KA, int KB>
__global__ __launch_bounds__(256)
void prep_bfrag(const float* __restrict__ W, __hip_bfloat16* __restrict__ Bws)
{
    constexpr int PA = KA/2, PB = KB/2;
    int t = blockIdx.x * 256 + threadIdx.x;
    if (t >= 25*13*64) return;
    int lane = t & 63;
    int f = (t >> 6) % 13;
    int p = t / (64*13);
    int pi = p/5, pj = p%5;
    bool c1a = (pi >= 2-PA && pi <= 2+PA && pj >= 2-PB && pj <= 2+PB);
    int slen = c1a ? 400 : KA*KB*16;
    int n = lane & 15;
    __hip_bfloat16 vals[8];
    #pragma unroll
    for (int j = 0; j < 8; ++j) {
        int kk = f*32 + ((lane>>4)*8) + j;
        float v = 0.f;
        if (kk < slen) {
            int sp = kk >> 4, c = kk & 15;
            int dsh, dsw;
            if (c1a) { dsh = sp/5 - 2;  dsw = sp%5 - 2;  }
            else     { dsh = sp/KB - PA; dsw = sp%KB - PB; }
            if (n < 8) {
                if (c1a && n < O)
                    v = W[((((size_t)(n*16 + c)*KA + (pi-2+PA))*KB + (pj-2+PB))*5 + (dsh+2))*5 + (dsw+2)];
            } else {
                int o = n - 8;
                if (o < O && dsh >= -PA && dsh <= PA && dsw >= -PB && dsw <= PB)
                    v = W[((((size_t)(o*16 + c)*KA + (dsh+PA))*KB + (dsw+PB))*5 + pi)*5 + pj];
            }
        }
        vals[j] = __float2bfloat16(v);
    }
    *reinterpret_cast<short8*>(Bws + (size_t)t * 8) = *reinterpret_cast<const short8*>(vals);
}

// ---------------------------------------------------------------------------
// Layer-2/3 MFMA conv (round-2 kernel + XCD swizzle)
// ---------------------------------------------------------------------------
__device__ inline void load_plane_regs(const __hip_bfloat16* __restrict__ X,
                                       int b, int h1, int w1, int p, int tid,
                                       short8& s0, short8& s1)
{
    int pi = p/5, pj = p%5;
    int hh = h1 + pi - 2, ww = w1 + pj - 2;
    short8 z = {};
    if ((unsigned)hh < 16u && (unsigned)ww < 16u) {
        const short8* src = reinterpret_cast<const short8*>(X)
                          + ((size_t)((b*16 + hh)*16 + ww) << 9);
        s0 = src[tid];
        s1 = src[tid + 256];
    } else { s0 = z; s1 = z; }
}

template<int O, int KA, int KB, bool OUTBF16>
__global__ __launch_bounds__(256)
void conv_mfma(const __hip_bfloat16* __restrict__ X,
               const __hip_bfloat16* __restrict__ Bws,
               const float* __restrict__ bias,
               void* __restrict__ Yout, int obase)
{
    constexpr int PA = KA/2, PB = KB/2;
    constexpr bool FULLALL = (KA == 5 && KB == 5);
    constexpr int NFC = 13;
    constexpr int NFO = (KA*KB*16 + 31)/32;
    __shared__ __align__(16) char lbuf[12800];

    const int tid = threadIdx.x, lane = tid & 63, wid = tid >> 6;
    int blk = (blockIdx.x & 7) * (gridDim.x >> 3) + (blockIdx.x >> 3);  // XCD swizzle
    const int w1 = blk & 15, h1 = (blk >> 4) & 15, b = blk >> 8;
    const int g = lane >> 4, lane15 = lane & 15;

    for (int i = tid; i < 3200; i += 256) reinterpret_cast<int*>(lbuf)[i] = 0;

    unsigned offsC[NFC];
    #pragma unroll
    for (int f = 0; f < NFC; ++f) {
        int kk = f*32 + g*8;
        unsigned off = 0;
        if (kk < 400) {
            int sp = kk >> 4, half = (kk >> 3) & 1;
            int dsh = sp/5 - 2, dsw = sp%5 - 2;
            off = (unsigned)(half*6400 + ((dsh+2)*20 + (dsw+2))*16);
        }
        offsC[f] = off;
    }
    unsigned offsO[NFO];
    if (!FULLALL) {
        #pragma unroll
        for (int f = 0; f < NFO; ++f) {
            int kk = f*32 + g*8;
            unsigned off = 0;
            if (kk < KA*KB*16) {
                int sp = kk >> 4, half = (kk >> 3) & 1;
                int dsh = sp/KB - PA, dsw = sp%KB - PB;
                off = (unsigned)(half*6400 + ((dsh+2)*20 + (dsw+2))*16);
            }
            offsO[f] = off;
        }
    }

    f32x4 acc[4] = {{0,0,0,0},{0,0,0,0},{0,0,0,0},{0,0,0,0}};
    const unsigned aterm = (unsigned)(lane15*16 + wid*4*320);

    const int dst0 = (tid&1)*6400 + (((tid>>1)>>4)+2)*320 + (((tid>>1)&15)+2)*16;
    const int dst1 = dst0 + 2560;

    short8 st0, st1;
    load_plane_regs(X, b, h1, w1, 0, tid, st0, st1);

    for (int p = 0; p < 25; ++p) {
        __syncthreads();
        *reinterpret_cast<short8*>(lbuf + dst0) = st0;
        *reinterpret_cast<short8*>(lbuf + dst1) = st1;
        __syncthreads();
        if (p < 24) load_plane_regs(X, b, h1, w1, p+1, tid, st0, st1);

        int pi = p/5, pj = p%5;
        const short8* bp = reinterpret_cast<const short8*>(Bws) + (size_t)p*13*64 + lane;
        bool center = FULLALL || (pi >= 2-PA && pi <= 2+PA && pj >= 2-PB && pj <= 2+PB);
        if (center) {
            #pragma unroll
            for (int f = 0; f < NFC; ++f) {
                short8 bf = bp[f*64];
                #pragma unroll
                for (int mt = 0; mt < 4; ++mt) {
                    short8 a = *reinterpret_cast<const short8*>(lbuf + offsC[f] + aterm + mt*320);
                    acc[mt] = __builtin_amdgcn_mfma_f32_16x16x32_bf16(a, bf, acc[mt], 0, 0, 0);
                }
            }
        } else {
            #pragma unroll
            for (int f = 0; f < NFO; ++f) {
                short8 bf = bp[f*64];
                #pragma unroll
                for (int mt = 0; mt < 4; ++mt) {
                    short8 a = *reinterpret_cast<const short8*>(lbuf + offsO[f] + aterm + mt*320);
                    acc[mt] = __builtin_amdgcn_mfma_f32_16x16x32_bf16(a, bf, acc[mt], 0, 0, 0);
                }
            }
        }
    }

    const int o = lane15 & 7;
    const float bv = (o < O) ? bias[o] : 0.f;
    #pragma unroll
    for (int mt = 0; mt < 4; ++mt) {
        #pragma unroll
        for (int r = 0; r < 4; ++r) {
            float own = acc[mt][r];
            float oth = __shfl_xor(own, 8);
            if (lane15 < 8 && o < O) {
                float y = fmaxf(own + bv, 0.f) + fmaxf(oth + bv, 0.f);
                int h2 = wid*4 + mt, w2 = g*4 + r;
                size_t pos = (((size_t)b*256 + h1*16 + w1) << 8) + h2*16 + w2;
                if (OUTBF16)
                    reinterpret_cast<__hip_bfloat16*>(Yout)[pos*16 + obase + o] = __float2bfloat16(y);
                else
                    reinterpret_cast<float*>(Yout)[pos] = y;
            }
        }
    }
}

// ---------------------------------------------------------------------------
extern "C" void kernel_launch(void* const* d_in, const int* in_sizes, int n_in,
                              void* d_out, int out_size, void* d_ws, size_t ws_size,
                              hipStream_t stream) {
    const float* x   = (const float*)d_in[0];
    const float* w00 = (const float*)d_in[1];
    const float* b00 = (const float*)d_in[2];
    const float* w01 = (const float*)d_in[3];
    const float* b01 = (const float*)d_in[4];
    const float* w10 = (const float*)d_in[5];
    const float* b10 = (const float*)d_in[6];
    const float* w11 = (const float*)d_in[7];
    const float* b11 = (const float*)d_in[8];
    const float* w2  = (const float*)d_in[9];
    const float* b2  = (const float*)d_in[10];

    const int B = in_sizes[0] / SP;   // 4

    __hip_bfloat16* X1   = (__hip_bfloat16*)d_ws;                 // B*SP*16
    __hip_bfloat16* X2   = X1 + (size_t)B * SP * 16;              // B*SP*16
    __hip_bfloat16* Bw10 = X2 + (size_t)B * SP * 16;              // 25*13*64*8
    __hip_bfloat16* Bw11 = Bw10 + 25*13*64*8;
    __hip_bfloat16* Bw2  = Bw11 + 25*13*64*8;
    __hip_bfloat16* Bl1a = Bw2  + 25*13*64*8;                     // 25*64*8
    __hip_bfloat16* Bl1b = Bl1a + 25*64*8;
    __hip_bfloat16* Xim  = Bl1b + 25*64*8;                        // B*SP*32

    const int ximTotal = B * SP * 4;
    hipLaunchKernelGGL(build_xim, dim3((ximTotal + 255)/256), dim3(256), 0, stream,
                       x, Xim, ximTotal);

    hipLaunchKernelGGL((prep_bl1<3,3>), dim3(7), dim3(256), 0, stream, w00, Bl1a);
    hipLaunchKernelGGL((prep_bl1<5,5>), dim3(7), dim3(256), 0, stream, w01, Bl1b);

    dim3 blockP(256), gridP(82);
    hipLaunchKernelGGL((prep_bfrag<8,3,3>), gridP, blockP, 0, stream, w10, Bw10);
    hipLaunchKernelGGL((prep_bfrag<8,5,5>), gridP, blockP, 0, stream, w11, Bw11);
    hipLaunchKernelGGL((prep_bfrag<1,5,5>), gridP, blockP, 0, stream, w2,  Bw2);

    dim3 block(256), grid(B * 256);
    hipLaunchKernelGGL(conv_mfma_l1, grid, block, 0, stream,
                       Xim, Bl1a, Bl1b, b00, b01, X1);

    hipLaunchKernelGGL((conv_mfma<8,3,3,true>),  grid, block, 0, stream,
                       X1, Bw10, b10, (void*)X2, 0);
    hipLaunchKernelGGL((conv_mfma<8,5,5,true>),  grid, block, 0, stream,
                       X1, Bw11, b11, (void*)X2, 8);
    hipLaunchKernelGGL((conv_mfma<1,5,5,false>), grid, block, 0, stream,
                       X2, Bw2,  b2,  d_out, 0);
}